// Round 14
// baseline (147.415 us; speedup 1.0000x reference)
//
#include <hip/hip_runtime.h>
#include <hip/hip_bf16.h>

#define B_ 4
#define N_ 2048
#define C_ 256
#define H_ 4
#define D_ 64

typedef __attribute__((ext_vector_type(8))) short bf16x8;
typedef __attribute__((ext_vector_type(4))) float f32x4;

#define LOG2E 1.4426950408889634f

static __device__ inline unsigned short f2bf(float f) {
    unsigned u = __builtin_bit_cast(unsigned, f);
    unsigned r = (u + 0x7fffu + ((u >> 16) & 1u)) >> 16;
    return (unsigned short)r;
}
static __device__ inline float bf2f(unsigned short h) {
    unsigned u = ((unsigned)h) << 16;
    return __builtin_bit_cast(float, u);
}
static __device__ inline unsigned pack2(float a, float b) {
    __hip_bfloat162 h = __float22bfloat162_rn(make_float2(a, b));
    unsigned u;
    __builtin_memcpy(&u, &h, 4);
    return u;
}
static __device__ inline unsigned pks(unsigned short a, unsigned short b) {
    return (unsigned)a | ((unsigned)b << 16);
}
static __device__ inline bf16x8 ld_frag(const unsigned short* p) {
    return __builtin_bit_cast(bf16x8, *(const uint4*)p);
}

// ---------------- cvt: x/qkv_w/proj_w -> bf16; Pext table (A-side key ext);
// maxP^2; nb init ----------------
__global__ __launch_bounds__(256) void cvt_kernel(
    const float* __restrict__ x, const float* __restrict__ qkv_w,
    const float* __restrict__ proj_w, const float* __restrict__ Pm,
    unsigned short* __restrict__ xb, unsigned short* __restrict__ wqb,
    unsigned short* __restrict__ wpb, unsigned short* __restrict__ pext,
    unsigned* __restrict__ nb)
{
    __shared__ float red[256];
    const int bid = blockIdx.x, tid = threadIdx.x;
    const float* s; unsigned short* d; int i;
    if (bid < 1024)      { s = x;      d = xb;  i = (bid * 256 + tid) * 8; }
    else if (bid < 1120) { s = qkv_w;  d = wqb; i = ((bid - 1024) * 256 + tid) * 8; }
    else                 { s = proj_w; d = wpb; i = ((bid - 1120) * 256 + tid) * 8; }
    float4 a = *(const float4*)(s + i);
    float4 b = *(const float4*)(s + i + 4);
    uint4 u;
    u.x = pack2(a.x, a.y); u.y = pack2(a.z, a.w);
    u.z = pack2(b.x, b.y); u.w = pack2(b.z, b.w);
    *(uint4*)(d + i) = u;

    if (bid == 1151) {   // P extras: pext rows, maxP^2, nb init
        float mp = 0.f;
        for (int r8 = 0; r8 < 8; ++r8) {
            int n = tid * 8 + r8;
            float p0 = Pm[n * 3 + 0], p1 = Pm[n * 3 + 1], p2 = Pm[n * 3 + 2];
            mp = fmaxf(mp, p0 * p0 + p1 * p1 + p2 * p2);
            unsigned short u0 = f2bf(p0), u1 = f2bf(p1), u2 = f2bf(p2);
            unsigned short v0 = f2bf(p0 - bf2f(u0));
            unsigned short v1 = f2bf(p1 - bf2f(u1));
            unsigned short v2 = f2bf(p2 - bf2f(u2));
            // A-side key ext: [u0,u1,u2,u0,u1,u2,v0,v1 | v2,0.. | 0 x16]
            uint4 q0, q1, z = {0u, 0u, 0u, 0u};
            q0.x = pks(u0, u1); q0.y = pks(u2, u0);
            q0.z = pks(u1, u2); q0.w = pks(v0, v1);
            q1.x = pks(v2, 0); q1.y = 0u; q1.z = 0u; q1.w = 0u;
            unsigned short* pr = &pext[(size_t)n * 32];
            *(uint4*)(pr + 0) = q0;
            *(uint4*)(pr + 8) = q1;
            *(uint4*)(pr + 16) = z;
            *(uint4*)(pr + 24) = z;
        }
        red[tid] = mp;
        __syncthreads();
        for (int w = 128; w > 0; w >>= 1) {
            if (tid < w) red[tid] = fmaxf(red[tid], red[tid + w]);
            __syncthreads();
        }
        if (tid < 16) nb[tid] = 0u;
        if (tid == 0) nb[16] = __builtin_bit_cast(unsigned, red[0]);
    }
}

// ---------------- QKV GEMM: bf16, 128x128 tile, 4 waves 2x2, BK=32 ----------
// Q pre-scaled by 0.125*log2e. V transposed, TRUE key order: vt[bh][d][n].
__global__ __launch_bounds__(256) void qkv_gemm(
    const unsigned short* __restrict__ xb, const unsigned short* __restrict__ wb,
    const float* __restrict__ bias, unsigned short* __restrict__ qb,
    unsigned short* __restrict__ kb, unsigned short* __restrict__ vt)
{
    __shared__ __align__(16) unsigned short As[128 * 40];
    __shared__ __align__(16) unsigned short Bs[128 * 40];
    const int m0 = blockIdx.x * 128, o0 = blockIdx.y * 128;
    const int tid = threadIdx.x;
    const int wave = tid >> 6, lane = tid & 63, quad = lane >> 4, l16 = lane & 15;
    const int wy = wave >> 1, wx = wave & 1;

    f32x4 acc[4][4];
    #pragma unroll
    for (int i = 0; i < 4; ++i)
        #pragma unroll
        for (int j = 0; j < 4; ++j) acc[i][j] = (f32x4){0.f, 0.f, 0.f, 0.f};

    const int srow = tid >> 1, soff = (tid & 1) * 16;

    for (int k0 = 0; k0 < 256; k0 += 32) {
        __syncthreads();
        {
            const unsigned short* sa = &xb[(size_t)(m0 + srow) * 256 + k0 + soff];
            const unsigned short* sb = &wb[(size_t)(o0 + srow) * 256 + k0 + soff];
            *(uint4*)&As[srow * 40 + soff + 0] = *(const uint4*)(sa + 0);
            *(uint4*)&As[srow * 40 + soff + 8] = *(const uint4*)(sa + 8);
            *(uint4*)&Bs[srow * 40 + soff + 0] = *(const uint4*)(sb + 0);
            *(uint4*)&Bs[srow * 40 + soff + 8] = *(const uint4*)(sb + 8);
        }
        __syncthreads();
        bf16x8 a[4], b[4];
        #pragma unroll
        for (int mt = 0; mt < 4; ++mt) a[mt] = ld_frag(&As[(wy * 64 + mt * 16 + l16) * 40 + quad * 8]);
        #pragma unroll
        for (int nt = 0; nt < 4; ++nt) b[nt] = ld_frag(&Bs[(wx * 64 + nt * 16 + l16) * 40 + quad * 8]);
        #pragma unroll
        for (int mt = 0; mt < 4; ++mt)
            #pragma unroll
            for (int nt = 0; nt < 4; ++nt)
                acc[mt][nt] = __builtin_amdgcn_mfma_f32_16x16x32_bf16(a[mt], b[nt], acc[mt][nt], 0, 0, 0);
    }

    const int sec = o0 + wx * 64;
    const int three = sec >> 8;
    const int h = (sec >> 6) & 3;
    const int b = m0 >> 11;
    float bv[4];
    #pragma unroll
    for (int nt = 0; nt < 4; ++nt) bv[nt] = bias[sec + nt * 16 + l16];

    if (three == 2) {
        // V^T true order: value (n, d) -> vt[bh][d][n]; r-contiguous n pack
        const int n64 = (m0 + wy * 64) & 2047;
        const size_t bh64 = ((size_t)b * H_ + h) * 64;
        #pragma unroll
        for (int nt = 0; nt < 4; ++nt) {
            int dd = nt * 16 + l16;
            #pragma unroll
            for (int mt = 0; mt < 4; ++mt) {
                ushort4 v;
                v.x = f2bf(acc[mt][nt][0] + bv[nt]);
                v.y = f2bf(acc[mt][nt][1] + bv[nt]);
                v.z = f2bf(acc[mt][nt][2] + bv[nt]);
                v.w = f2bf(acc[mt][nt][3] + bv[nt]);
                *(ushort4*)&vt[(bh64 + dd) * N_ + n64 + mt * 16 + quad * 4] = v;
            }
        }
    } else {
        unsigned short* dst = (three == 0) ? qb : kb;
        float sc = (three == 0) ? (0.125f * LOG2E) : 1.0f;
        #pragma unroll
        for (int mt = 0; mt < 4; ++mt)
            #pragma unroll
            for (int r = 0; r < 4; ++r) {
                int n = (m0 + wy * 64 + mt * 16 + quad * 4 + r) & 2047;
                size_t rowbase = (((size_t)b * H_ + h) * N_ + n) * D_;
                #pragma unroll
                for (int nt = 0; nt < 4; ++nt)
                    dst[rowbase + nt * 16 + l16] = f2bf((acc[mt][nt][r] + bv[nt]) * sc);
            }
    }
}

// ---------------- norm: maxK^2 per bh ----------------
__global__ __launch_bounds__(256) void norm_kernel(
    const unsigned short* __restrict__ kb, unsigned* __restrict__ nb)
{
    __shared__ float red[256];
    const int bh = blockIdx.x, chunk = blockIdx.y, tid = threadIdx.x;
    const size_t base = (size_t)bh * N_ * D_ + (size_t)(chunk * 256 + tid) * D_;
    float sk = 0.f;
    #pragma unroll
    for (int j4 = 0; j4 < 8; ++j4) {
        union { uint4 u; unsigned short s[8]; } kv;
        kv.u = *(const uint4*)&kb[base + j4 * 8];
        #pragma unroll
        for (int j = 0; j < 8; ++j) { float v = bf2f(kv.s[j]); sk += v * v; }
    }
    red[tid] = sk;
    __syncthreads();
    for (int w = 128; w > 0; w >>= 1) {
        if (tid < w) red[tid] = fmaxf(red[tid], red[tid + w]);
        __syncthreads();
    }
    if (tid == 0) atomicMax(&nb[bh], __builtin_bit_cast(unsigned, red[0]));
}

// ---------------- attention: S^T = K·Q^T, persistent Q in LDS, streaming K/V
// from global into MFMA A-operands; static-bound softmax; 1 barrier/tile.
#define QLD 104   // Qs row: 64 q-dims + 32 ext + 8 pad
#define PLD 72

__global__ __launch_bounds__(256) void attn_kernel(
    const unsigned short* __restrict__ qb, const unsigned short* __restrict__ kb,
    const unsigned short* __restrict__ vt, const unsigned short* __restrict__ pext,
    const float* __restrict__ Rm, const float* __restrict__ Pm,
    const float* __restrict__ ps_ptr, const unsigned* __restrict__ nb,
    unsigned short* __restrict__ Opart, float* __restrict__ ml)
{
    __shared__ __align__(16) unsigned short Qs[64 * QLD];     // [query][dim|ext]
    __shared__ __align__(16) unsigned short Pb[2][64 * PLD];  // [query][key], dbuf
    __shared__ float MqS[64];

    const int bh = blockIdx.y, b = bh >> 2;
    const int i0 = blockIdx.x * 64;
    const int split = blockIdx.z;
    const int tid = threadIdx.x;
    const int wave = tid >> 6, lane = tid & 63;
    const int quad = lane >> 4, l16 = lane & 15;
    const float ps = ps_ptr[0];

    const size_t base = (size_t)bh * N_ * D_;
    const unsigned short* qg = qb + base;
    const unsigned short* kg = kb + base;
    const unsigned short* vg = vt + base;   // rows of length N_

    // stage Qs dims (once)
    {
        int row = tid >> 2, c = (tid & 3) * 16;
        const unsigned short* src = &qg[(size_t)(i0 + row) * D_ + c];
        *(uint4*)&Qs[row * QLD + c + 0] = *(const uint4*)(src + 0);
        *(uint4*)&Qs[row * QLD + c + 8] = *(const uint4*)(src + 8);
    }
    // ext cols (B-side query ext) + static bound Mq (once)
    if (tid < 64) {
        const int q = i0 + tid;
        float p0 = Pm[q * 3 + 0], p1 = Pm[q * 3 + 1], p2 = Pm[q * 3 + 2];
        float sc = ps * LOG2E;
        unsigned short ah[3], al[3];
        float an2 = 0.f;
        #pragma unroll
        for (int c = 0; c < 3; ++c) {
            float a = (Rm[b * 9 + c * 3 + 0] * p0 + Rm[b * 9 + c * 3 + 1] * p1
                     + Rm[b * 9 + c * 3 + 2] * p2) * sc;
            an2 += a * a;
            ah[c] = f2bf(a);
            al[c] = f2bf(a - bf2f(ah[c]));
        }
        // [ah0,ah1,ah2,al0,al1,al2,ah0,ah1 | ah2,0.. | 0 x16]
        uint4 e0, e1, z = {0u, 0u, 0u, 0u};
        e0.x = pks(ah[0], ah[1]); e0.y = pks(ah[2], al[0]);
        e0.z = pks(al[1], al[2]); e0.w = pks(ah[0], ah[1]);
        e1.x = pks(ah[2], 0); e1.y = 0u; e1.z = 0u; e1.w = 0u;
        unsigned short* er = &Qs[tid * QLD + 64];
        *(uint4*)(er + 0) = e0;
        *(uint4*)(er + 8) = e1;
        *(uint4*)(er + 16) = z;
        *(uint4*)(er + 24) = z;
        // q-norm (global re-read, one-time)
        float qn = 0.f;
        #pragma unroll
        for (int c8 = 0; c8 < 8; ++c8) {
            union { uint4 u; unsigned short s[8]; } qv;
            qv.u = *(const uint4*)&qg[(size_t)q * D_ + c8 * 8];
            #pragma unroll
            for (int j = 0; j < 8; ++j) { float v = bf2f(qv.s[j]); qn += v * v; }
        }
        float maxK = sqrtf(__builtin_bit_cast(float, nb[bh]));
        float maxP = sqrtf(__builtin_bit_cast(float, nb[16]));
        MqS[tid] = sqrtf(qn) * maxK + sqrtf(an2) * maxP + 1.0f;
    }
    __syncthreads();

    float Mrow[4];
    #pragma unroll
    for (int t = 0; t < 4; ++t) Mrow[t] = MqS[16 * t + l16];

    const bf16x8 ones = (bf16x8){0x3F80,0x3F80,0x3F80,0x3F80,0x3F80,0x3F80,0x3F80,0x3F80};

    f32x4 o_acc[4], lacc;
    #pragma unroll
    for (int t = 0; t < 4; ++t) o_acc[t] = (f32x4){0.f, 0.f, 0.f, 0.f};
    lacc = (f32x4){0.f, 0.f, 0.f, 0.f};

    const int jbeg = split * (N_ / 2);
    const int NT = (N_ / 2) / 64;
    const int wkey = wave * 16 + l16;   // S A-side key row within tile
    const int vrow = wave * 16 + l16;   // PV A-side d row

    int buf = 0;
    for (int jt = 0; jt < NT; ++jt) {
        const int j0 = jbeg + jt * 64;
        // streaming A-side loads straight from global (no LDS staging)
        bf16x8 ka0 = ld_frag(&kg[(size_t)(j0 + wkey) * D_ + quad * 8]);
        bf16x8 ka1 = ld_frag(&kg[(size_t)(j0 + wkey) * D_ + 32 + quad * 8]);
        bf16x8 kae = ld_frag(&pext[(size_t)(j0 + wkey) * 32 + quad * 8]);
        bf16x8 va0 = ld_frag(&vg[(size_t)vrow * N_ + j0 + quad * 8]);
        bf16x8 va1 = ld_frag(&vg[(size_t)vrow * N_ + j0 + 32 + quad * 8]);

        // S^T strip: keys (this wave's 16) x 64 queries, bias folded via ext
        f32x4 s[4];
        #pragma unroll
        for (int t = 0; t < 4; ++t) {
            const unsigned short* br = &Qs[(16 * t + l16) * QLD];
            f32x4 c = {0.f, 0.f, 0.f, 0.f};
            c = __builtin_amdgcn_mfma_f32_16x16x32_bf16(ka0, ld_frag(br + quad * 8), c, 0, 0, 0);
            c = __builtin_amdgcn_mfma_f32_16x16x32_bf16(ka1, ld_frag(br + 32 + quad * 8), c, 0, 0, 0);
            c = __builtin_amdgcn_mfma_f32_16x16x32_bf16(kae, ld_frag(br + 64 + quad * 8), c, 0, 0, 0);
            s[t] = c;
        }

        // P = exp2(s - M[q]); keys r-contiguous -> b64 pack into Pb[buf]
        #pragma unroll
        for (int t = 0; t < 4; ++t) {
            uint2 w;
            w.x = pack2(exp2f(s[t][0] - Mrow[t]), exp2f(s[t][1] - Mrow[t]));
            w.y = pack2(exp2f(s[t][2] - Mrow[t]), exp2f(s[t][3] - Mrow[t]));
            *(uint2*)&Pb[buf][(16 * t + l16) * PLD + wave * 16 + quad * 4] = w;
        }
        __syncthreads();   // all P strips visible; dbuf makes 1 barrier/tile safe

        // O^T += V^T P^T (A = vt direct-global, B = Pb rows)
        #pragma unroll
        for (int ks = 0; ks < 2; ++ks) {
            bf16x8 av = ks ? va1 : va0;
            #pragma unroll
            for (int t = 0; t < 4; ++t) {
                bf16x8 bp = ld_frag(&Pb[buf][(16 * t + l16) * PLD + ks * 32 + quad * 8]);
                o_acc[t] = __builtin_amdgcn_mfma_f32_16x16x32_bf16(av, bp, o_acc[t], 0, 0, 0);
            }
            // l for this wave's query range
            bf16x8 bl = ld_frag(&Pb[buf][(16 * wave + l16) * PLD + ks * 32 + quad * 8]);
            lacc = __builtin_amdgcn_mfma_f32_16x16x32_bf16(ones, bl, lacc, 0, 0, 0);
        }
        buf ^= 1;
    }

    // epilogue: O^T regs pack along d -> Opart[q][d] (R13 layout), l per q
    const size_t pbase = (size_t)(split * 16 + bh) * N_;
    #pragma unroll
    for (int t = 0; t < 4; ++t) {
        ushort4 v;
        v.x = f2bf(o_acc[t][0]); v.y = f2bf(o_acc[t][1]);
        v.z = f2bf(o_acc[t][2]); v.w = f2bf(o_acc[t][3]);
        *(ushort4*)&Opart[(pbase + i0 + 16 * t + l16) * D_ + wave * 16 + quad * 4] = v;
    }
    if (quad == 0)
        ml[pbase + i0 + wave * 16 + l16] = lacc[0];
}

// ---------------- Output projection: fused sum-merge (static M), bf16 weights --
__global__ __launch_bounds__(256) void proj_gemm(
    const unsigned short* __restrict__ Opart, const float* __restrict__ ml,
    const unsigned short* __restrict__ wb, const float* __restrict__ bias,
    float* __restrict__ out)
{
    __shared__ __align__(16) unsigned short As[64 * 40];
    __shared__ __align__(16) unsigned short Bs[64 * 40];
    const int m0 = blockIdx.x * 64, o0 = blockIdx.y * 64;
    const int tid = threadIdx.x;
    const int wave = tid >> 6, lane = tid & 63, quad = lane >> 4, l16 = lane & 15;

    const int srow = tid >> 2, scb = (tid & 3) * 8;
    const int sm = m0 + srow, sb = sm >> 11, sn = sm & 2047;

    float invh[4];
    #pragma unroll
    for (int h = 0; h < 4; ++h) {
        size_t r1 = (size_t)(sb * 4 + h) * N_ + sn;
        invh[h] = 1.f / (ml[r1] + ml[r1 + 16 * (size_t)N_]);
    }

    f32x4 acc[4];
    #pragma unroll
    for (int j = 0; j < 4; ++j) acc[j] = (f32x4){0.f, 0.f, 0.f, 0.f};

    for (int k0 = 0; k0 < 256; k0 += 32) {
        const int h = k0 >> 6;
        const int d0 = (k0 & 63) + scb;
        __syncthreads();
        {
            size_t r1 = (size_t)(sb * 4 + h) * N_ + sn;
            union { uint4 u; unsigned short s[8]; } a1, a2;
            a1.u = *(const uint4*)&Opart[r1 * D_ + d0];
            a2.u = *(const uint4*)&Opart[(r1 + 16 * (size_t)N_) * D_ + d0];
            float w = invh[h];
            uint4 mv;
            unsigned* mp = (unsigned*)&mv;
            #pragma unroll
            for (int j = 0; j < 4; ++j)
                mp[j] = pack2((bf2f(a1.s[2*j]) + bf2f(a2.s[2*j])) * w,
                              (bf2f(a1.s[2*j+1]) + bf2f(a2.s[2*j+1])) * w);
            *(uint4*)&As[srow * 40 + scb] = mv;
            *(uint4*)&Bs[srow * 40 + scb] = *(const uint4*)&wb[(size_t)(o0 + srow) * 256 + k0 + scb];
        }
        __syncthreads();
        bf16x8 a = ld_frag(&As[(wave * 16 + l16) * 40 + quad * 8]);
        #pragma unroll
        for (int nt = 0; nt < 4; ++nt) {
            bf16x8 b = ld_frag(&Bs[(nt * 16 + l16) * 40 + quad * 8]);
            acc[nt] = __builtin_amdgcn_mfma_f32_16x16x32_bf16(a, b, acc[nt], 0, 0, 0);
        }
    }

    float bv[4];
    #pragma unroll
    for (int nt = 0; nt < 4; ++nt) bv[nt] = bias[o0 + nt * 16 + l16];
    #pragma unroll
    for (int r = 0; r < 4; ++r) {
        int m = m0 + wave * 16 + quad * 4 + r;
        #pragma unroll
        for (int nt = 0; nt < 4; ++nt)
            out[(size_t)m * 256 + o0 + nt * 16 + l16] = acc[nt][r] + bv[nt];
    }
}

extern "C" void kernel_launch(void* const* d_in, const int* in_sizes, int n_in,
                              void* d_out, int out_size, void* d_ws, size_t ws_size,
                              hipStream_t stream) {
    const float* x       = (const float*)d_in[0];
    const float* Rm      = (const float*)d_in[1];
    const float* Pm      = (const float*)d_in[2];
    const float* qkv_w   = (const float*)d_in[3];
    const float* qkv_b   = (const float*)d_in[4];
    const float* proj_w  = (const float*)d_in[5];
    const float* proj_b  = (const float*)d_in[6];
    const float* pos_scl = (const float*)d_in[7];
    float* out = (float*)d_out;

    const size_t NE = (size_t)B_ * H_ * N_ * D_;   // 2,097,152
    unsigned short* xb    = (unsigned short*)d_ws; // 4 MB
    unsigned short* wqb   = xb   + NE;             // 768*256
    unsigned short* wpb   = wqb  + 768 * 256;      // 256*256
    unsigned short* pextb = wpb  + 256 * 256;      // 2048*32
    unsigned short* qb    = pextb + 2048 * 32;     // 4 MB each
    unsigned short* kb    = qb   + NE;
    unsigned short* vtb   = kb   + NE;
    unsigned short* opart = vtb  + NE;             // 2*NE = 8 MB
    float*          mlb   = (float*)(opart + 2 * NE);  // 2*16*2048 floats
    unsigned*       nb    = (unsigned*)(mlb + 2 * 16 * 2048);  // 17 uints

    cvt_kernel<<<1152, 256, 0, stream>>>(x, qkv_w, proj_w, Pm, xb, wqb, wpb, pextb, nb);
    qkv_gemm<<<dim3(64, 6), 256, 0, stream>>>(xb, wqb, qkv_b, qb, kb, vtb);
    norm_kernel<<<dim3(16, 8), 256, 0, stream>>>(kb, nb);
    attn_kernel<<<dim3(32, 16, 2), 256, 0, stream>>>(qb, kb, vtb, pextb, Rm, Pm, pos_scl, nb, opart, mlb);
    proj_gemm<<<dim3(128, 4), 256, 0, stream>>>(opart, mlb, wpb, proj_b, out);
}